// Round 4
// baseline (156.758 us; speedup 1.0000x reference)
//
#include <hip/hip_runtime.h>
#include <hip/hip_bf16.h>

// Chamfer distance, B=16, N=M=4096, D=3, fp32 — MFMA formulation.
//
// d2(s,t) = |s|^2 + |t|^2 - 2 s.t computed in ONE K=32 bf16 MFMA per 16x16
// tile, with hi/lo bf16 coordinate splitting for fp32-grade accuracy:
//   A(src)[k]: [sh sh sl  fs_hi fs_lo 1 1  0...]   (sh=bf16(s), sl=bf16(s-sh))
//   B(tgt)[k]: [-2th -2tl -2th  1 1 ft_hi ft_lo 0...]
//   dot = |s|^2 + |t|^2 - 2(sh.th + sh.tl + sl.th) = d2 + 2 sl.tl (~1e-4 err)
// One pass over the symmetric 4096x4096 tile grid gives BOTH directions:
// row-mins = min over tgt (cham_x), col-mins = min over src (cham_y).

#define BATCH 16
#define NPTS  4096
#define NMINS (2 * BATCH * NPTS)       // 131072
#define NPER  (BATCH * NPTS)           // 65536 points per role

typedef __attribute__((ext_vector_type(8))) short short8;
typedef __attribute__((ext_vector_type(4))) float float4v;

union U4S8 { uint4 u; short8 s; };

__device__ inline unsigned int bfb(float v) {
    __hip_bfloat16 h = __float2bfloat16(v);
    unsigned short u; __builtin_memcpy(&u, &h, 2);
    return (unsigned int)u;
}
__device__ inline float bff(float v) {            // round-trip to bf16 value
    return __bfloat162float(__float2bfloat16(v));
}

#define ONEB 0x3F80u

// ---------- kernel 0: build augmented bf16 vectors (32 B per point) ----------
__global__ __launch_bounds__(256) void aug_kernel(
    const float* __restrict__ src, const float* __restrict__ tgt,
    uint4* __restrict__ augA, uint4* __restrict__ augB)
{
    int i = blockIdx.x * 256 + threadIdx.x;       // 0 .. 131071
    int role = i >> 16;                           // 0: src->A, 1: tgt->B
    int p = i & (NPER - 1);
    const float* base = role ? tgt : src;
    float x = base[3 * p + 0];
    float y = base[3 * p + 1];
    float z = base[3 * p + 2];

    float xhf = bff(x), yhf = bff(y), zhf = bff(z);
    float xlf = x - xhf, ylf = y - yhf, zlf = z - zhf;
    float f = fmaf(x, x, fmaf(y, y, z * z));
    float fhf = bff(f), flf = f - fhf;

    unsigned int xh = bfb(xhf), yh = bfb(yhf), zh = bfb(zhf);
    unsigned int xl = bfb(xlf), yl = bfb(ylf), zl = bfb(zlf);
    unsigned int fh = bfb(fhf), fl = bfb(flf);

    uint4 w0, w1;
    if (role == 0) {
        // A slots: xh yh zh | xh yh zh | xl yl zl | fh fl 1 1 0 0 0
        w0 = make_uint4(xh | (yh << 16), zh | (xh << 16),
                        yh | (zh << 16), xl | (yl << 16));
        w1 = make_uint4(zl | (fh << 16), fl | (ONEB << 16), ONEB, 0u);
        uint4* out = augA + (size_t)p * 2;
        out[0] = w0; out[1] = w1;
    } else {
        // B slots: -2xh -2yh -2zh | -2xl -2yl -2zl | -2xh -2yh -2zh | 1 1 fh fl 0 0 0
        unsigned int a = bfb(-2.0f * xhf), b = bfb(-2.0f * yhf), c = bfb(-2.0f * zhf);
        unsigned int d = bfb(-2.0f * xlf), e = bfb(-2.0f * ylf), g = bfb(-2.0f * zlf);
        w0 = make_uint4(a | (b << 16), c | (d << 16),
                        e | (g << 16), a | (b << 16));
        w1 = make_uint4(c | (ONEB << 16), ONEB | (fh << 16), fl, 0u);
        uint4* out = augB + (size_t)p * 2;
        out[0] = w0; out[1] = w1;
    }
}

// ---------- kernel 1: MFMA tiles + directional min folds ----------
// Grid: 16 batches x 32 row-blocks x 32 col-blocks = 16384 blocks of 256.
// Block tile: 128x128. Wave tile: 32 rows x 128 cols (G=2 row-tiles, H=8).
// No LDS, no barriers: frags load from L1/L2, mins merge via global atomicMin.
__global__ __launch_bounds__(256) void chamfer_mfma_kernel(
    const uint4* __restrict__ augA, const uint4* __restrict__ augB,
    unsigned int* __restrict__ mins)
{
    int blk = blockIdx.x;
    const int bn = blk & 31; blk >>= 5;
    const int bm = blk & 31; blk >>= 5;
    const int b  = blk;                               // 0..15

    const int lane = threadIdx.x & 63;
    const int w    = threadIdx.x >> 6;
    const int q    = lane >> 4;                        // quad 0..3
    const int c    = lane & 15;                        // 0..15

    const int R  = bm * 128 + w * 32;                  // wave's row base
    const int C0 = bn * 128;                           // block's col base

    const uint4* Ab = augA + (size_t)b * NPTS * 2;
    const uint4* Bb = augB + (size_t)b * NPTS * 2;

    // Fragments: lane supplies k = q*8 + j. Quads 2,3 (k>=16) are zero pad.
    short8 afr[2], bfr[8];
    if (q < 2) {
#pragma unroll
        for (int g = 0; g < 2; g++) {
            U4S8 t; t.u = Ab[(size_t)(R + g * 16 + c) * 2 + q]; afr[g] = t.s;
        }
#pragma unroll
        for (int h = 0; h < 8; h++) {
            U4S8 t; t.u = Bb[(size_t)(C0 + h * 16 + c) * 2 + q]; bfr[h] = t.s;
        }
    } else {
        short8 zz = {0, 0, 0, 0, 0, 0, 0, 0};
#pragma unroll
        for (int g = 0; g < 2; g++) afr[g] = zz;
#pragma unroll
        for (int h = 0; h < 8; h++) bfr[h] = zz;
    }

    // acc[g][h][r] = d2[row = R + g*16 + q*4 + r][col = C0 + h*16 + c]
    float4v acc[2][8];
#pragma unroll
    for (int g = 0; g < 2; g++)
#pragma unroll
        for (int h = 0; h < 8; h++)
            acc[g][h] = float4v{0.f, 0.f, 0.f, 0.f};
#pragma unroll
    for (int h = 0; h < 8; h++)
#pragma unroll
        for (int g = 0; g < 2; g++)
            acc[g][h] = __builtin_amdgcn_mfma_f32_16x16x32_bf16(
                afr[g], bfr[h], acc[g][h], 0, 0, 0);

    // ---- row mins (cham_x: min over tgt cols) ----
    float rm[2][4];
#pragma unroll
    for (int g = 0; g < 2; g++)
#pragma unroll
        for (int r = 0; r < 4; r++) {
            float m0 = fminf(fminf(acc[g][0][r], acc[g][1][r]), acc[g][2][r]);
            float m1 = fminf(fminf(acc[g][3][r], acc[g][4][r]), acc[g][5][r]);
            float m2 = fminf(fminf(acc[g][6][r], acc[g][7][r]), m0);
            rm[g][r] = fminf(m1, m2);
        }
#pragma unroll
    for (int mask = 1; mask <= 8; mask <<= 1)
#pragma unroll
        for (int g = 0; g < 2; g++)
#pragma unroll
            for (int r = 0; r < 4; r++)
                rm[g][r] = fminf(rm[g][r], __shfl_xor(rm[g][r], mask, 64));
    if (c == 0) {
        unsigned int* rowm = mins + (size_t)b * NPTS;       // dir 0
#pragma unroll
        for (int g = 0; g < 2; g++)
#pragma unroll
            for (int r = 0; r < 4; r++) {
                float v = fmaxf(rm[g][r], 0.0f);
                atomicMin(&rowm[R + g * 16 + q * 4 + r], __float_as_uint(v));
            }
    }

    // ---- col mins (cham_y: min over src rows) ----
    float cm[8];
#pragma unroll
    for (int h = 0; h < 8; h++) {
        float m0 = fminf(fminf(acc[0][h][0], acc[0][h][1]), acc[0][h][2]);
        float m1 = fminf(fminf(acc[0][h][3], acc[1][h][0]), acc[1][h][1]);
        float m2 = fminf(fminf(acc[1][h][2], acc[1][h][3]), m0);
        cm[h] = fminf(m1, m2);
    }
#pragma unroll
    for (int mask = 16; mask <= 32; mask <<= 1)
#pragma unroll
        for (int h = 0; h < 8; h++)
            cm[h] = fminf(cm[h], __shfl_xor(cm[h], mask, 64));
    if (q == 0) {                                           // lanes 0..15
        unsigned int* colm = mins + (size_t)(BATCH + b) * NPTS;  // dir 1
#pragma unroll
        for (int h = 0; h < 8; h++) {
            float v = fmaxf(cm[h], 0.0f);
            atomicMin(&colm[C0 + h * 16 + c], __float_as_uint(v));
        }
    }
}

// ---------- kernel 2: final sum (proven in R1) ----------
__global__ __launch_bounds__(256) void chamfer_reduce_kernel(
    const unsigned int* __restrict__ mins, float* __restrict__ out)
{
    float s = 0.0f;
    for (int idx = blockIdx.x * blockDim.x + threadIdx.x; idx < NMINS;
         idx += gridDim.x * blockDim.x) {
        s += __uint_as_float(mins[idx]);
    }
#pragma unroll
    for (int off = 32; off > 0; off >>= 1) s += __shfl_down(s, off, 64);
    __shared__ float wsum[4];
    int lane = threadIdx.x & 63;
    int w = threadIdx.x >> 6;
    if (lane == 0) wsum[w] = s;
    __syncthreads();
    if (threadIdx.x == 0) {
        float tot = wsum[0] + wsum[1] + wsum[2] + wsum[3];
        atomicAdd(out, tot * (1.0f / (float)NPTS));
    }
}

extern "C" void kernel_launch(void* const* d_in, const int* in_sizes, int n_in,
                              void* d_out, int out_size, void* d_ws, size_t ws_size,
                              hipStream_t stream)
{
    const float* src = (const float*)d_in[0];
    const float* tgt = (const float*)d_in[1];
    float* out = (float*)d_out;

    unsigned int* mins = (unsigned int*)d_ws;
    uint4* augA = (uint4*)(mins + NMINS);                 // 65536 x 32 B
    uint4* augB = augA + (size_t)NPER * 2;                // 65536 x 32 B

    hipMemsetAsync(mins, 0xFF, (size_t)NMINS * sizeof(unsigned int), stream);
    hipMemsetAsync(out, 0, sizeof(float), stream);

    aug_kernel<<<NPER * 2 / 256, 256, 0, stream>>>(src, tgt, augA, augB);
    chamfer_mfma_kernel<<<BATCH * 32 * 32, 256, 0, stream>>>(augA, augB, mins);
    chamfer_reduce_kernel<<<128, 256, 0, stream>>>(mins, out);
}

// Round 5
// 88.176 us; speedup vs baseline: 1.7778x; 1.7778x over previous
//
#include <hip/hip_runtime.h>
#include <hip/hip_bf16.h>

// Chamfer distance, B=16, N=M=4096, D=3, fp32 — MFMA 32x32x16, atomic-free.
//
// d2(s,t) = |s|^2+|t|^2-2 s.t via ONE K=16 bf16 MFMA per 32x32 tile with
// hi/lo bf16 coordinate splitting (R4-verified slot content, absmax 0):
//   A: [xh yh zh xh yh zh xl yl | zl fh fl 1 1 0 0 0]          (s terms)
//   B: [-2xh -2yh -2zh -2xl -2yl -2zl -2xh -2yh | -2zh 1 1 fh fl 0 0 0] (t)
// Two passes (dir 0/1): each block owns 128 query rows, loops all 4096
// target cols -> FINAL row-mins in registers -> one atomicAdd per block.
// B-side staged to LDS in 512-point chunks (double-buffered, async
// global_load_lds width=16), lo/hi halves in separate arrays so both the
// staging and ds_read_b128 are the contiguous conflict-free pattern.

#define BATCH  16
#define NPTS   4096
#define NPER   (BATCH * NPTS)          // 65536 points per role
#define CHUNKC 512                     // target points staged per chunk
#define NCHUNKS (NPTS / CHUNKC)        // 8

typedef __attribute__((ext_vector_type(8)))  short short8;
typedef __attribute__((ext_vector_type(16))) float float16;

union U4S8 { uint4 u; short8 s; };

__device__ inline unsigned int bfb(float v) {
    __hip_bfloat16 h = __float2bfloat16(v);
    unsigned short u; __builtin_memcpy(&u, &h, 2);
    return (unsigned int)u;
}
__device__ inline float bff(float v) { return __bfloat162float(__float2bfloat16(v)); }

#define ONEB 0x3F80u

// ---------- kernel 0: build augmented bf16 records, lo/hi split ----------
// i = role*NPER + p ; role 0 = src, 1 = tgt. Every point gets both an
// A-layout record (used when its set is the query side) and a B-layout
// record (target side). lo = slots 0..7, hi = slots 8..15.
__global__ __launch_bounds__(256) void aug_kernel(
    const float* __restrict__ src, const float* __restrict__ tgt,
    uint4* __restrict__ layAlo, uint4* __restrict__ layAhi,
    uint4* __restrict__ layBlo, uint4* __restrict__ layBhi)
{
    int i = blockIdx.x * 256 + threadIdx.x;       // 0 .. 2*NPER-1
    int role = i >> 16;
    int p = i & (NPER - 1);
    const float* base = role ? tgt : src;
    float x = base[3 * p + 0];
    float y = base[3 * p + 1];
    float z = base[3 * p + 2];

    float xhf = bff(x), yhf = bff(y), zhf = bff(z);
    float xlf = x - xhf, ylf = y - yhf, zlf = z - zhf;
    float f = fmaf(x, x, fmaf(y, y, z * z));
    float fhf = bff(f), flf = f - fhf;

    unsigned xh = bfb(xhf), yh = bfb(yhf), zh = bfb(zhf);
    unsigned xl = bfb(xlf), yl = bfb(ylf), zl = bfb(zlf);
    unsigned fh = bfb(fhf), fl = bfb(flf);

    // A layout (R4-verified)
    uint4 aw0 = make_uint4(xh | (yh << 16), zh | (xh << 16),
                           yh | (zh << 16), xl | (yl << 16));
    uint4 aw1 = make_uint4(zl | (fh << 16), fl | (ONEB << 16), ONEB, 0u);
    // B layout (R4-verified)
    unsigned a = bfb(-2.0f * xhf), b = bfb(-2.0f * yhf), c = bfb(-2.0f * zhf);
    unsigned d = bfb(-2.0f * xlf), e = bfb(-2.0f * ylf), g = bfb(-2.0f * zlf);
    uint4 bw0 = make_uint4(a | (b << 16), c | (d << 16),
                           e | (g << 16), a | (b << 16));
    uint4 bw1 = make_uint4(c | (ONEB << 16), ONEB | (fh << 16), fl, 0u);

    layAlo[i] = aw0; layAhi[i] = aw1;
    layBlo[i] = bw0; layBhi[i] = bw1;
}

// ---------- kernel 1: row-strip MFMA + final row-min + block sum ----------
// Grid: dir(2) x batch(16) x strip(32 of 128 rows) = 1024 blocks x 256.
// Wave w owns rows strip*128 + w*32 .. +31 (m = lane&31).
// A frag: lane holds uint4[lane>>5] of its row point (k = (lane>>5)*8+j).
// B frag: lane holds uint4[lane>>5] of target point (n = lane&31).
// C/D layout: col = lane&31, row = (r&3) + 8*(r>>2) + 4*(lane>>5).
__global__ __launch_bounds__(256, 4) void chamfer_mfma_kernel(
    const uint4* __restrict__ layAlo, const uint4* __restrict__ layAhi,
    const uint4* __restrict__ layBlo, const uint4* __restrict__ layBhi,
    float* __restrict__ out)
{
    __shared__ uint4 sbuf[2][2][CHUNKC];    // [buf][half][point] = 32 KB
    __shared__ float wsum[4];

    int blk = blockIdx.x;
    const int strip = blk & 31; blk >>= 5;
    const int b     = blk & 15; blk >>= 4;
    const int dir   = blk;

    const int lane = threadIdx.x & 63;
    const int w    = threadIdx.x >> 6;
    const int half = lane >> 5;
    const int l5   = lane & 31;

    const size_t Aoff = (size_t)dir * NPER + (size_t)b * NPTS;       // query role = dir
    const size_t Boff = (size_t)(1 - dir) * NPER + (size_t)b * NPTS; // target role

    // A fragment, held for the whole kernel.
    U4S8 at; at.u = (half ? layAhi : layAlo)[Aoff + strip * 128 + w * 32 + l5];
    const short8 afr = at.s;

    const uint4* Blo = layBlo + Boff;
    const uint4* Bhi = layBhi + Boff;

    // Stage chunk c into buffer bi: 1024 uint4, linear li = w*256 + j*64 + lane.
    // LDS dest = wave-uniform base + lane*16 (global_load_lds contract).
    auto stage = [&](int c, int bi) {
#pragma unroll
        for (int j = 0; j < 4; j++) {
            int li = w * 256 + j * 64;               // wave-uniform
            int hf = li >> 9;
            int pt = li & (CHUNKC - 1);
            const uint4* gsrc = (hf ? Bhi : Blo) + c * CHUNKC + pt + lane;
            __builtin_amdgcn_global_load_lds(
                (const __attribute__((address_space(1))) unsigned int*)gsrc,
                (__attribute__((address_space(3))) unsigned int*)&sbuf[bi][hf][pt],
                16, 0, 0);
        }
    };

    const float16 z16 = {0.f,0.f,0.f,0.f,0.f,0.f,0.f,0.f,
                         0.f,0.f,0.f,0.f,0.f,0.f,0.f,0.f};
    float rm[16];
#pragma unroll
    for (int r = 0; r < 16; r++) rm[r] = 1e30f;

    stage(0, 0);
    for (int c = 0; c < NCHUNKS; c++) {
        __syncthreads();                  // stage(c) complete; buf[(c+1)&1] free
        if (c + 1 < NCHUNKS) stage(c + 1, (c + 1) & 1);
        const int bi = c & 1;
#pragma unroll 2
        for (int j2 = 0; j2 < CHUNKC / 64; j2++) {       // 8 steps of 64 cols
            U4S8 t0, t1;
            t0.u = sbuf[bi][half][j2 * 64 + l5];
            t1.u = sbuf[bi][half][j2 * 64 + 32 + l5];
            float16 a0 = __builtin_amdgcn_mfma_f32_32x32x16_bf16(afr, t0.s, z16, 0, 0, 0);
            float16 a1 = __builtin_amdgcn_mfma_f32_32x32x16_bf16(afr, t1.s, z16, 0, 0, 0);
#pragma unroll
            for (int r = 0; r < 16; r++)
                rm[r] = fminf(fminf(a0[r], a1[r]), rm[r]);   // v_min3_f32
        }
    }

    // Lane-fold: min over cols = over lane&31 (masks 1..16, stays in half).
#pragma unroll
    for (int mask = 1; mask <= 16; mask <<= 1)
#pragma unroll
        for (int r = 0; r < 16; r++)
            rm[r] = fminf(rm[r], __shfl_xor(rm[r], mask, 64));

    // Each lane's 16 slots are 16 distinct final rows (x half = 32 rows/wave).
    float s = 0.0f;
#pragma unroll
    for (int r = 0; r < 16; r++) s += fmaxf(rm[r], 0.0f);
    s += __shfl_xor(s, 32, 64);           // add the other half's 16 rows

    if (lane == 0) wsum[w] = s;
    __syncthreads();
    if (threadIdx.x == 0)
        atomicAdd(out, (wsum[0] + wsum[1] + wsum[2] + wsum[3]) * (1.0f / (float)NPTS));
}

extern "C" void kernel_launch(void* const* d_in, const int* in_sizes, int n_in,
                              void* d_out, int out_size, void* d_ws, size_t ws_size,
                              hipStream_t stream)
{
    const float* src = (const float*)d_in[0];
    const float* tgt = (const float*)d_in[1];
    float* out = (float*)d_out;

    uint4* layAlo = (uint4*)d_ws;                 // 2*NPER uint4 = 2 MB each
    uint4* layAhi = layAlo + 2 * NPER;
    uint4* layBlo = layAhi + 2 * NPER;
    uint4* layBhi = layBlo + 2 * NPER;

    hipMemsetAsync(out, 0, sizeof(float), stream);
    aug_kernel<<<2 * NPER / 256, 256, 0, stream>>>(src, tgt,
                                                   layAlo, layAhi, layBlo, layBhi);
    chamfer_mfma_kernel<<<2 * BATCH * 32, 256, 0, stream>>>(layAlo, layAhi,
                                                            layBlo, layBhi, out);
}

// Round 6
// 79.715 us; speedup vs baseline: 1.9665x; 1.1061x over previous
//
#include <hip/hip_runtime.h>
#include <hip/hip_bf16.h>

// Chamfer distance, B=16, N=M=4096, D=3, fp32 — single fused MFMA kernel.
//
// d2(s,t) = |s|^2+|t|^2-2 s.t via ONE K=16 bf16 mfma_f32_32x32x16 per 32x32
// tile with hi/lo bf16 splitting (slot layout verified absmax==0 in R4+R5):
//   A: [xh yh zh xh yh zh xl yl | zl fh fl 1 1 0 0 0]           (query s)
//   B: [-2xh -2yh -2zh -2xl -2yl -2zl -2xh -2yh | -2zh 1 1 fh fl 0 0 0] (t)
// Grid: dir(2) x batch(16) x strip(16 of 256 rows) = 512 blocks x 256 thr.
// Wave owns 2 row-groups of 32 rows -> each B-fragment ds_read feeds 2 MFMAs.
// B-records built IN-KERNEL per 512-pt chunk into double-buffered LDS
// (ds_write_b128, contiguous stride-16 = conflict-free); A-records built
// once in registers. Row-mins are final per block -> one atomicAdd each.

#define BATCH   16
#define NPTS    4096
#define CHUNKC  512
#define NCHUNKS (NPTS / CHUNKC)        // 8
#define NSTRIPS 16                     // 4096 / 256 rows per block

typedef __attribute__((ext_vector_type(8)))  short short8;
typedef __attribute__((ext_vector_type(16))) float float16;

union U4S8 { uint4 u; short8 s; };

__device__ inline unsigned int bfb(float v) {
    __hip_bfloat16 h = __float2bfloat16(v);
    unsigned short u; __builtin_memcpy(&u, &h, 2);
    return (unsigned int)u;
}
__device__ inline float bff(float v) { return __bfloat162float(__float2bfloat16(v)); }

#define ONEB 0x3F80u

__device__ inline void buildA(float x, float y, float z, uint4& w0, uint4& w1) {
    float xhf = bff(x), yhf = bff(y), zhf = bff(z);
    float f = fmaf(x, x, fmaf(y, y, z * z));
    float fhf = bff(f);
    unsigned xh = bfb(xhf), yh = bfb(yhf), zh = bfb(zhf);
    unsigned xl = bfb(x - xhf), yl = bfb(y - yhf), zl = bfb(z - zhf);
    unsigned fh = bfb(fhf), fl = bfb(f - fhf);
    w0 = make_uint4(xh | (yh << 16), zh | (xh << 16),
                    yh | (zh << 16), xl | (yl << 16));
    w1 = make_uint4(zl | (fh << 16), fl | (ONEB << 16), ONEB, 0u);
}

__device__ inline void buildB(float x, float y, float z, uint4& w0, uint4& w1) {
    float xhf = bff(x), yhf = bff(y), zhf = bff(z);
    float f = fmaf(x, x, fmaf(y, y, z * z));
    float fhf = bff(f);
    unsigned a = bfb(-2.0f * xhf), b = bfb(-2.0f * yhf), c = bfb(-2.0f * zhf);
    unsigned d = bfb(-2.0f * (x - xhf)), e = bfb(-2.0f * (y - yhf)),
             g = bfb(-2.0f * (z - zhf));
    unsigned fh = bfb(fhf), fl = bfb(f - fhf);
    w0 = make_uint4(a | (b << 16), c | (d << 16),
                    e | (g << 16), a | (b << 16));
    w1 = make_uint4(c | (ONEB << 16), ONEB | (fh << 16), fl, 0u);
}

__global__ __launch_bounds__(256, 2) void chamfer_fused_kernel(
    const float* __restrict__ src, const float* __restrict__ tgt,
    float* __restrict__ out)
{
    __shared__ uint4 sbuf[2][2][CHUNKC];    // [buf][half][pt] = 32 KB
    __shared__ float wsum[4];

    int blk = blockIdx.x;
    const int strip = blk & (NSTRIPS - 1); blk >>= 4;
    const int b     = blk & 15;            blk >>= 4;
    const int dir   = blk;

    const int lane = threadIdx.x & 63;
    const int w    = threadIdx.x >> 6;
    const int half = lane >> 5;
    const int l5   = lane & 31;

    const float* Araw = (dir ? tgt : src) + (size_t)b * NPTS * 3;  // queries
    const float* Braw = (dir ? src : tgt) + (size_t)b * NPTS * 3;  // targets

    // A fragments: 2 row-groups of 32 rows per wave, built once.
    short8 afr[2];
#pragma unroll
    for (int g = 0; g < 2; g++) {
        int row = strip * 256 + g * 128 + w * 32 + l5;
        uint4 w0, w1;
        buildA(Araw[3 * row], Araw[3 * row + 1], Araw[3 * row + 2], w0, w1);
        U4S8 t; t.u = half ? w1 : w0;
        afr[g] = t.s;
    }

    // Convert chunk c of B into LDS buffer bi (2 pts per thread, stride 256
    // keeps the ds_write_b128s contiguous across the wave = conflict-free).
    auto convert = [&](int c, int bi) {
#pragma unroll
        for (int k = 0; k < 2; k++) {
            int lp = (int)threadIdx.x + k * 256;
            int p  = c * CHUNKC + lp;
            uint4 w0, w1;
            buildB(Braw[3 * p], Braw[3 * p + 1], Braw[3 * p + 2], w0, w1);
            sbuf[bi][0][lp] = w0;
            sbuf[bi][1][lp] = w1;
        }
    };

    const float16 z16 = {0.f,0.f,0.f,0.f,0.f,0.f,0.f,0.f,
                         0.f,0.f,0.f,0.f,0.f,0.f,0.f,0.f};
    float rm[2][16];
#pragma unroll
    for (int g = 0; g < 2; g++)
#pragma unroll
        for (int r = 0; r < 16; r++) rm[g][r] = 1e30f;

    convert(0, 0);
    for (int c = 0; c < NCHUNKS; c++) {
        __syncthreads();                 // buf[c&1] fully written; prior reads done
        if (c + 1 < NCHUNKS) convert(c + 1, (c + 1) & 1);
        const int bi = c & 1;
#pragma unroll 2
        for (int j2 = 0; j2 < CHUNKC / 64; j2++) {       // 8 steps of 64 cols
            U4S8 t0, t1;
            t0.u = sbuf[bi][half][j2 * 64 + l5];
            t1.u = sbuf[bi][half][j2 * 64 + 32 + l5];
            float16 a00 = __builtin_amdgcn_mfma_f32_32x32x16_bf16(afr[0], t0.s, z16, 0, 0, 0);
            float16 a01 = __builtin_amdgcn_mfma_f32_32x32x16_bf16(afr[0], t1.s, z16, 0, 0, 0);
            float16 a10 = __builtin_amdgcn_mfma_f32_32x32x16_bf16(afr[1], t0.s, z16, 0, 0, 0);
            float16 a11 = __builtin_amdgcn_mfma_f32_32x32x16_bf16(afr[1], t1.s, z16, 0, 0, 0);
#pragma unroll
            for (int r = 0; r < 16; r++) {
                rm[0][r] = fminf(fminf(a00[r], a01[r]), rm[0][r]);   // v_min3
                rm[1][r] = fminf(fminf(a10[r], a11[r]), rm[1][r]);
            }
        }
    }

    // Col-fold within half (masks 1..16 over lane&31); each lane then holds
    // 2x16 final rows for its half; shfl 32 merges the halves' sums.
#pragma unroll
    for (int mask = 1; mask <= 16; mask <<= 1)
#pragma unroll
        for (int g = 0; g < 2; g++)
#pragma unroll
            for (int r = 0; r < 16; r++)
                rm[g][r] = fminf(rm[g][r], __shfl_xor(rm[g][r], mask, 64));

    float s = 0.0f;
#pragma unroll
    for (int g = 0; g < 2; g++)
#pragma unroll
        for (int r = 0; r < 16; r++) s += fmaxf(rm[g][r], 0.0f);
    s += __shfl_xor(s, 32, 64);

    if (lane == 0) wsum[w] = s;
    __syncthreads();
    if (threadIdx.x == 0)
        atomicAdd(out, (wsum[0] + wsum[1] + wsum[2] + wsum[3]) * (1.0f / (float)NPTS));
}

extern "C" void kernel_launch(void* const* d_in, const int* in_sizes, int n_in,
                              void* d_out, int out_size, void* d_ws, size_t ws_size,
                              hipStream_t stream)
{
    const float* src = (const float*)d_in[0];
    const float* tgt = (const float*)d_in[1];
    float* out = (float*)d_out;

    hipMemsetAsync(out, 0, sizeof(float), stream);
    chamfer_fused_kernel<<<2 * BATCH * NSTRIPS, 256, 0, stream>>>(src, tgt, out);
}